// Round 9
// baseline (161.018 us; speedup 1.0000x reference)
//
#include <hip/hip_runtime.h>
#include <hip/hip_bf16.h>

// TDCPQueryAttentionPool fused kernel for MI355X (gfx950).
// B=8, N=4096, M=4, E=512, H=8, d=64. tokens = 32768.
//
// R9 = R8 (2-step phases, 4 barriers, 4 rotating 16KB x-buffers, counted
// vmcnt, setprio) with the 80KB LDS delivered legally: dynamic LDS via
// extern __shared__ + hipFuncSetAttribute (unconditional, every call).
// R8 crashed on 80KB STATIC __shared__ (>64KB static limit).

typedef float  f32x4  __attribute__((ext_vector_type(4)));
typedef float  f32x16 __attribute__((ext_vector_type(16)));
typedef short  short8 __attribute__((ext_vector_type(8)));
typedef unsigned int u32x2 __attribute__((ext_vector_type(2)));

__device__ __forceinline__ unsigned short f2bf(float f) {
  unsigned int x = __float_as_uint(f);
  unsigned int r = (x + 0x7fffu + ((x >> 16) & 1u)) >> 16;  // RNE
  return (unsigned short)r;
}

__device__ __forceinline__ u32x2 pack4(const f32x4& a) {
  u32x2 r;
  asm("v_cvt_pk_bf16_f32 %0, %1, %2" : "=v"(r[0]) : "v"(a[0]), "v"(a[1]));
  asm("v_cvt_pk_bf16_f32 %0, %1, %2" : "=v"(r[1]) : "v"(a[2]), "v"(a[3]));
  return r;
}

__device__ __forceinline__ void mfma32(f32x16& c, short8 a, short8 b) {
  asm("v_mfma_f32_32x32x16_bf16 %0, %1, %2, %0" : "+v"(c) : "v"(a), "v"(b));
}
__device__ __forceinline__ void mfma16(f32x4& c, short8 a, short8 b) {
  asm("v_mfma_f32_16x16x32_bf16 %0, %1, %2, %0" : "+v"(c) : "v"(a), "v"(b));
}

__device__ __forceinline__ void gld4f(f32x4& d, const float* p) {
  asm volatile("global_load_dwordx4 %0, %1, off" : "=v"(d) : "v"(p));
}
__device__ __forceinline__ void gld4s(short8& d, const unsigned short* p) {
  asm volatile("global_load_dwordx4 %0, %1, off" : "=v"(d) : "v"(p));
}

__device__ __forceinline__ void wxv4(f32x4& a, f32x4& b, f32x4& c, f32x4& d) {
  asm volatile("s_waitcnt vmcnt(4)" : "+v"(a), "+v"(b), "+v"(c), "+v"(d));
}
// pack-wait: ties both lx banks, vmcnt(16)
__device__ __forceinline__ void wlx16(f32x4& a, f32x4& b, f32x4& c, f32x4& d,
                                      f32x4& e, f32x4& f, f32x4& g, f32x4& h) {
  asm volatile("s_waitcnt vmcnt(16)"
               : "+v"(a), "+v"(b), "+v"(c), "+v"(d),
                 "+v"(e), "+v"(f), "+v"(g), "+v"(h));
}
__device__ __forceinline__ void wbv16(short8& a, short8& b, short8& c, short8& d,
                                      short8& e, short8& f, short8& g, short8& h) {
  asm volatile("s_waitcnt vmcnt(16)"
               : "+v"(a), "+v"(b), "+v"(c), "+v"(d),
                 "+v"(e), "+v"(f), "+v"(g), "+v"(h));
}
__device__ __forceinline__ void wbv8(short8& a, short8& b, short8& c, short8& d,
                                     short8& e, short8& f, short8& g, short8& h) {
  asm volatile("s_waitcnt vmcnt(8)"
               : "+v"(a), "+v"(b), "+v"(c), "+v"(d),
                 "+v"(e), "+v"(f), "+v"(g), "+v"(h));
}
__device__ __forceinline__ void wbv0(short8& a, short8& b, short8& c, short8& d,
                                     short8& e, short8& f, short8& g, short8& h) {
  asm volatile("s_waitcnt vmcnt(0)"
               : "+v"(a), "+v"(b), "+v"(c), "+v"(d),
                 "+v"(e), "+v"(f), "+v"(g), "+v"(h));
}

// ---------------------------------------------------------------------------
// K0: precompute (verbatim from R1-R7; correctness-verified).
// ---------------------------------------------------------------------------
__global__ void __launch_bounds__(512) tdcp_k0(
    const float* __restrict__ q_param, const float* __restrict__ in_w,
    const float* __restrict__ in_b, const float* __restrict__ out_w,
    float* __restrict__ scoreb, unsigned short* __restrict__ wscB,
    unsigned short* __restrict__ WvB, unsigned short* __restrict__ WoB)
{
  const int tid = threadIdx.x;
  const int blk = blockIdx.x;
  if (blk < 8) {
    const int h = blk;
    __shared__ float qls[512];
    __shared__ float qs[64];
    qls[tid] = q_param[tid];
    __syncthreads();
    {
      const int io = tid >> 3, sub = tid & 7;
      const float* wrow = in_w + (size_t)(h * 64 + io) * 512;
      float v = 0.f;
      #pragma unroll 8
      for (int ee = 0; ee < 64; ++ee) {
        const int e = sub + (ee << 3);
        v += wrow[e] * qls[e];
      }
      v += __shfl_xor(v, 1); v += __shfl_xor(v, 2); v += __shfl_xor(v, 4);
      if (sub == 0) qs[io] = (v + in_b[h * 64 + io]) * 0.125f;
    }
    __syncthreads();
    {
      const int e = tid;
      const float* wk = in_w + (size_t)(512 + h * 64) * 512 + e;
      float v = 0.f;
      #pragma unroll 8
      for (int jj = 0; jj < 64; ++jj) v += qs[jj] * wk[jj * 512];
      const int s32 = e >> 5, g = (e & 31) >> 3, j = e & 7;
      wscB[((s32 << 6) + h + (g << 4)) * 8 + j] = f2bf(v);
      wscB[((s32 << 6) + (h + 8) + (g << 4)) * 8 + j] = 0;
    }
    if (tid < 64) {
      float v = qs[tid] * in_b[512 + h * 64 + tid];
      v += __shfl_xor(v, 1);  v += __shfl_xor(v, 2);  v += __shfl_xor(v, 4);
      v += __shfl_xor(v, 8);  v += __shfl_xor(v, 16); v += __shfl_xor(v, 32);
      if (tid == 0) scoreb[h] = v;
    }
    if (blk == 0 && tid >= 64 && tid < 72) scoreb[tid - 56] = 0.f;
  } else {
    const int mb = blk - 8;
    const bool isWo = mb >= 64;
    const float* src = isWo ? out_w : (in_w + (size_t)1024 * 512);
    unsigned short* dst = isWo ? WoB : WvB;
    const int slot = ((mb & 63) << 9) + tid;
    const int ct = slot >> 11, kt = (slot >> 6) & 31, ln = slot & 63;
    const float* p = src + (size_t)(ct * 32 + (ln & 31)) * 512
                         + kt * 16 + ((ln >> 5) << 3);
    const f32x4 u0 = *(const f32x4*)(p);
    const f32x4 u1 = *(const f32x4*)(p + 4);
    short8 rr;
    rr[0] = (short)f2bf(u0[0]); rr[1] = (short)f2bf(u0[1]);
    rr[2] = (short)f2bf(u0[2]); rr[3] = (short)f2bf(u0[3]);
    rr[4] = (short)f2bf(u1[0]); rr[5] = (short)f2bf(u1[1]);
    rr[6] = (short)f2bf(u1[2]); rr[7] = (short)f2bf(u1[3]);
    *(short8*)(dst + slot * 8) = rr;
  }
}

// ---------------------------------------------------------------------------
// K1: fused attention-pool, 2-step-phase counted-vmcnt pipeline.
// Dynamic LDS 80KB: [0,64K) four 16K x-buffers (step s -> buf s&3);
// [64K,80K) wsc frags.  Epilogue reuse: omid [0,32K), av @64K, stats @68K.
// ---------------------------------------------------------------------------
__global__ void __launch_bounds__(512, 2) tdcp_k1(
    const float* __restrict__ f0, const float* __restrict__ f1,
    const float* __restrict__ f2, const float* __restrict__ f3,
    const float* __restrict__ in_b,
    const float* __restrict__ scoreb, const unsigned short* __restrict__ wscB,
    const unsigned short* __restrict__ WvB, const unsigned short* __restrict__ WoB,
    const float* __restrict__ out_b, const float* __restrict__ gamma,
    const float* __restrict__ beta, float* __restrict__ out)
{
  extern __shared__ __align__(16) char smem[];
  const int tid = threadIdx.x;
  const int w = tid >> 6;         // wave 0..7: owns output cols [64w,64w+64)
  const int l = tid & 63;
  const int tok0 = blockIdx.x << 5;

  // ---- wsc -> LDS @64K (16 KB) ----
  {
    const f32x4* wsrc = (const f32x4*)wscB;
    f32x4* wdst = (f32x4*)(smem + 65536);
    wdst[tid * 2] = wsrc[tid * 2];
    wdst[tid * 2 + 1] = wsrc[tid * 2 + 1];
  }

  // ---- staging map (R7-verified): row sr = t*4+m, c = tid&3 ----
  const int sr = tid >> 2;
  const int c = tid & 3;
  const int sm = sr & 3;
  const int stk = sr >> 2;
  const float* fsrc = (sm == 0 ? f0 : sm == 1 ? f1 : sm == 2 ? f2 : f3)
                      + (size_t)(tok0 + stk) * 512 + (c << 2);
  int wj[4];
  #pragma unroll
  for (int j = 0; j < 4; ++j)
    wj[j] = (j << 12) + ((sr >> 5) << 10) + ((c >> 1) << 9)
          + ((((sr & 31) << 4)) ^ (j << 5)) + ((c & 1) << 3);

  // ---- fragment-read bases (unchanged) ----
  const int aO = ((l >> 5) << 9) + ((l & 31) << 4);
  const int sBase = ((w >> 1) << 10) + (((l >> 4) & 1) << 9)
                  + ((((w & 1) << 4) | (l & 15)) << 4);
  const int ct0 = w << 1;
  const unsigned short* wv0 = WvB + (((ct0 * 32) << 6) + l) * 8;
  const unsigned short* wv1 = WvB + ((((ct0 + 1) * 32) << 6) + l) * 8;
  const unsigned short* wscL = (const unsigned short*)(smem + 65536);

  f32x16 acc[4][2];
  f32x4 sacc;
  #pragma unroll
  for (int i = 0; i < 4; ++i)
    #pragma unroll
    for (int cc = 0; cc < 2; ++cc)
      #pragma unroll
      for (int r = 0; r < 16; ++r) acc[i][cc][r] = 0.f;
  sacc[0] = sacc[1] = sacc[2] = sacc[3] = 0.f;

  f32x4 lx[2][4];   // bank0 = even steps, bank1 = odd steps
  short8 bb[2][8];  // bank0 = even-step B, bank1 = odd-step B

#define PACKSTEP(sc, bank) do {                                   \
    char* nb_ = smem + (((sc) & 3) << 14);                        \
    *(u32x2*)(nb_ + wj[0]) = pack4(lx[bank][0]);                  \
    *(u32x2*)(nb_ + wj[1]) = pack4(lx[bank][1]);                  \
    *(u32x2*)(nb_ + wj[2]) = pack4(lx[bank][2]);                  \
    *(u32x2*)(nb_ + wj[3]) = pack4(lx[bank][3]);                  \
  } while (0)

#define ISSUE_L(sc, bank) do {                                    \
    const float* p_ = fsrc + ((sc) << 6);                         \
    gld4f(lx[bank][0], p_);      gld4f(lx[bank][1], p_ + 16);     \
    gld4f(lx[bank][2], p_ + 32); gld4f(lx[bank][3], p_ + 48);     \
  } while (0)

#define ISSUE_B(sc, bank) do {                                    \
    gld4s(bb[bank][0], wv0 + ((sc) * 4 + 0) * 512);               \
    gld4s(bb[bank][1], wv1 + ((sc) * 4 + 0) * 512);               \
    gld4s(bb[bank][2], wv0 + ((sc) * 4 + 1) * 512);               \
    gld4s(bb[bank][3], wv1 + ((sc) * 4 + 1) * 512);               \
    gld4s(bb[bank][4], wv0 + ((sc) * 4 + 2) * 512);               \
    gld4s(bb[bank][5], wv1 + ((sc) * 4 + 2) * 512);               \
    gld4s(bb[bank][6], wv0 + ((sc) * 4 + 3) * 512);               \
    gld4s(bb[bank][7], wv1 + ((sc) * 4 + 3) * 512);               \
  } while (0)

#define COMPUTE(sc, bank) do {                                              \
    char* cur_ = smem + (((sc) & 3) << 14);                                 \
    const short8 sb0_ = *(const short8*)(wscL + (((2*(sc)) << 6) + l) * 8); \
    const short8 sb1_ = *(const short8*)(wscL + (((2*(sc)+1) << 6) + l) * 8);\
    __builtin_amdgcn_s_setprio(1);                                          \
    _Pragma("unroll")                                                       \
    for (int kt4 = 0; kt4 < 4; ++kt4) {                                     \
      _Pragma("unroll")                                                     \
      for (int rt = 0; rt < 4; ++rt) {                                      \
        const short8 a_ = *(const short8*)(cur_ + (kt4 << 12) + (rt << 10)  \
                                           + (aO ^ (kt4 << 5)));            \
        mfma32(acc[rt][0], a_, bb[bank][kt4 * 2]);                          \
        mfma32(acc[rt][1], a_, bb[bank][kt4 * 2 + 1]);                      \
      }                                                                     \
      if ((kt4 & 1) == 0) {                                                 \
        const int schunk_ = kt4 + (l >> 5);                                 \
        const short8 sa_ = *(const short8*)(cur_ + (schunk_ << 12)          \
                                            + (sBase ^ ((schunk_ & 3) << 5)));\
        mfma16(sacc, sa_, (kt4 == 0) ? sb0_ : sb1_);                        \
      }                                                                     \
    }                                                                       \
    __builtin_amdgcn_s_setprio(0);                                          \
  } while (0)

#define WPACK() wlx16(lx[0][0], lx[0][1], lx[0][2], lx[0][3],               \
                      lx[1][0], lx[1][1], lx[1][2], lx[1][3])
#define WB16(k) wbv16(bb[k][0], bb[k][1], bb[k][2], bb[k][3],               \
                      bb[k][4], bb[k][5], bb[k][6], bb[k][7])
#define WB8(k)  wbv8(bb[k][0], bb[k][1], bb[k][2], bb[k][3],                \
                     bb[k][4], bb[k][5], bb[k][6], bb[k][7])
#define WB0(k)  wbv0(bb[k][0], bb[k][1], bb[k][2], bb[k][3],                \
                     bb[k][4], bb[k][5], bb[k][6], bb[k][7])
#define BARRIER() do {                                            \
    asm volatile("s_waitcnt lgkmcnt(0)" ::: "memory");            \
    __builtin_amdgcn_s_barrier();                                 \
    asm volatile("" ::: "memory");                                \
  } while (0)

  // ---- prologue: L0,L1; pack(0),(1); L2,L3; B0,B1.  queue: L2,L3,B0,B1=24
  ISSUE_L(0, 0); ISSUE_L(1, 1);
  wxv4(lx[0][0], lx[0][1], lx[0][2], lx[0][3]);   // drain L0
  PACKSTEP(0, 0);
  ISSUE_L(2, 0);
  wxv4(lx[1][0], lx[1][1], lx[1][2], lx[1][3]);   // drain L1
  PACKSTEP(1, 1);
  ISSUE_L(3, 1);
  ISSUE_B(0, 0); ISSUE_B(1, 1);

  // ---- phase 0: steps 0,1 ----
  BARRIER();
  WPACK();            // <=16: drain L2,L3
  PACKSTEP(2, 0); PACKSTEP(3, 1);
  ISSUE_L(4, 0); ISSUE_L(5, 1);       // queue: B0,B1,L4,L5 = 24
  WB16(0);            // drain B0
  COMPUTE(0, 0);
  ISSUE_B(2, 0);                      // queue: B1,L4,L5,B2 = 24
  WB16(1);            // drain B1
  COMPUTE(1, 1);
  ISSUE_B(3, 1);                      // queue: L4,L5,B2,B3 = 24

  // ---- phase 1: steps 2,3 ----
  BARRIER();
  WPACK();            // <=16: drain L4,L5
  PACKSTEP(4, 0); PACKSTEP(5, 1);
  ISSUE_L(6, 0); ISSUE_L(7, 1);       // queue: B2,B3,L6,L7 = 24
  WB16(0);            // drain B2
  COMPUTE(2, 0);
  ISSUE_B(4, 0);                      // queue: B3,L6,L7,B4 = 24
  WB16(1);            // drain B3
  COMPUTE(3, 1);
  ISSUE_B(5, 1);                      // queue: L6,L7,B4,B5 = 24

  // ---- phase 2: steps 4,5 ----
  BARRIER();
  WPACK();            // <=16: drain L6,L7
  PACKSTEP(6, 0); PACKSTEP(7, 1);     // queue: B4,B5 = 16
  WB8(0);             // drain B4
  COMPUTE(4, 0);
  ISSUE_B(6, 0);                      // queue: B5,B6 = 16
  WB8(1);             // drain B5
  COMPUTE(5, 1);
  ISSUE_B(7, 1);                      // queue: B6,B7 = 16

  // ---- phase 3: steps 6,7 ----
  BARRIER();
  WB8(0);             // drain B6
  COMPUTE(6, 0);
  WB0(1);             // drain B7
  COMPUTE(7, 1);

  asm volatile("s_nop 7\n\ts_nop 7\n\ts_nop 7" ::);  // MFMA->VALU hazard pad
  __syncthreads();    // x-buffers & wsc region become reusable

  // ---- softmax over m (lane-local), write av[t][h] to LDS @64K ----
  {
    const int hh = l & 15;
    if (hh < 8) {
      const float sb = scoreb[hh];
      const float s0 = sacc[0] + sb, s1 = sacc[1] + sb;
      const float s2 = sacc[2] + sb, s3 = sacc[3] + sb;
      const float mx = fmaxf(fmaxf(s0, s1), fmaxf(s2, s3));
      const float e0 = __expf(s0 - mx), e1 = __expf(s1 - mx);
      const float e2 = __expf(s2 - mx), e3 = __expf(s3 - mx);
      const float inv = 1.f / (e0 + e1 + e2 + e3);
      f32x4 av; av[0] = e0 * inv; av[1] = e1 * inv; av[2] = e2 * inv; av[3] = e3 * inv;
      const int t = (w << 2) + (l >> 4);
      *(f32x4*)(smem + 65536 + (((t << 3) + hh) << 4)) = av;
    }
  }
  __syncthreads();

  // ---- blend: o_mid[t][f] = sum_m av*V + bv; scatter to frag LDS @0 ----
  {
    unsigned short* omid = (unsigned short*)(smem);
    #pragma unroll
    for (int c2 = 0; c2 < 2; ++c2) {
      const int ff = ((ct0 + c2) << 5) + (l & 31);
      const float bvf = in_b[1024 + ff];
      const int ktf = ff >> 4;
      const int laneL = ((l >> 3) & 1) << 5;
      const int elem = ff & 7;
      #pragma unroll
      for (int rt = 0; rt < 4; ++rt) {
        #pragma unroll
        for (int tt = 0; tt < 4; ++tt) {
          const int t = (rt << 3) + (tt << 1) + (l >> 5);
          const f32x4 av = *(const f32x4*)(smem + 65536 + (((t << 3) + w) << 4));
          const float o = av[0] * acc[rt][c2][tt * 4 + 0]
                        + av[1] * acc[rt][c2][tt * 4 + 1]
                        + av[2] * acc[rt][c2][tt * 4 + 2]
                        + av[3] * acc[rt][c2][tt * 4 + 3] + bvf;
          omid[((ktf << 6) + t + laneL) * 8 + elem] = f2bf(o);
        }
      }
    }
  }
  __syncthreads();

  // ---- out-projection GEMM: [32 x 512] x Wo^T (unroll 4, verified) ----
  f32x16 oa0, oa1;
  #pragma unroll
  for (int r = 0; r < 16; ++r) { oa0[r] = 0.f; oa1[r] = 0.f; }
  const unsigned short* wo0 = WoB + (((ct0 * 32) << 6) + l) * 8;
  const unsigned short* wo1 = WoB + ((((ct0 + 1) * 32) << 6) + l) * 8;
  const int a_off = l << 4;
  #pragma unroll 4
  for (int kt = 0; kt < 32; ++kt) {
    const short8 a = *(const short8*)(smem + (kt << 10) + a_off);
    mfma32(oa0, a, *(const short8*)(wo0 + kt * 512));
    mfma32(oa1, a, *(const short8*)(wo1 + kt * 512));
  }
  asm volatile("s_nop 7\n\ts_nop 7\n\ts_nop 7" ::);  // MFMA->VALU hazard pad

  // ---- LayerNorm: per-wave partial stats -> LDS @68K -> combine -> store ----
  {
    const int g0 = (ct0 << 5) + (l & 31);
    const int g1 = g0 + 32;
    const float ob0 = out_b[g0], ob1 = out_b[g1];
    const float gm0 = gamma[g0], gm1 = gamma[g1];
    const float bt0 = beta[g0],  bt1 = beta[g1];
    float* stats = (float*)(smem + 69632);  // [32][8 waves][2]
    #pragma unroll
    for (int r = 0; r < 16; ++r) {
      const float v0 = oa0[r] + ob0, v1 = oa1[r] + ob1;
      float s = v0 + v1, qq = v0 * v0 + v1 * v1;
      s += __shfl_xor(s, 16); qq += __shfl_xor(qq, 16);
      s += __shfl_xor(s, 8);  qq += __shfl_xor(qq, 8);
      s += __shfl_xor(s, 4);  qq += __shfl_xor(qq, 4);
      s += __shfl_xor(s, 2);  qq += __shfl_xor(qq, 2);
      s += __shfl_xor(s, 1);  qq += __shfl_xor(qq, 1);
      if ((l & 31) == 0) {
        const int t = (r & 3) + ((r >> 2) << 3) + ((l >> 5) << 2);
        stats[(t << 4) + (w << 1)] = s;
        stats[(t << 4) + (w << 1) + 1] = qq;
      }
    }
    __syncthreads();
    #pragma unroll
    for (int r = 0; r < 16; ++r) {
      const int t = (r & 3) + ((r >> 2) << 3) + ((l >> 5) << 2);
      const float* st = stats + (t << 4);
      float s = 0.f, qq = 0.f;
      #pragma unroll
      for (int ww = 0; ww < 8; ++ww) { s += st[2 * ww]; qq += st[2 * ww + 1]; }
      const float mu = s * 0.001953125f;
      const float rs = rsqrtf(qq * 0.001953125f - mu * mu + 1e-5f);
      const float v0 = oa0[r] + ob0, v1 = oa1[r] + ob1;
      float* op = out + (size_t)(tok0 + t) * 512;
      op[g0] = (v0 - mu) * rs * gm0 + bt0;
      op[g1] = (v1 - mu) * rs * gm1 + bt1;
    }
  }
#undef PACKSTEP
#undef ISSUE_L
#undef ISSUE_B
#undef COMPUTE
#undef WPACK
#undef WB16
#undef WB8
#undef WB0
#undef BARRIER
}

extern "C" void kernel_launch(void* const* d_in, const int* in_sizes, int n_in,
                              void* d_out, int out_size, void* d_ws, size_t ws_size,
                              hipStream_t stream) {
  const float* f0      = (const float*)d_in[0];
  const float* f1      = (const float*)d_in[1];
  const float* f2      = (const float*)d_in[2];
  const float* f3      = (const float*)d_in[3];
  const float* q_param = (const float*)d_in[4];
  const float* in_w    = (const float*)d_in[5];
  const float* in_b    = (const float*)d_in[6];
  const float* out_w   = (const float*)d_in[7];
  const float* out_b   = (const float*)d_in[8];
  const float* gamma   = (const float*)d_in[9];
  const float* beta    = (const float*)d_in[10];
  float* out = (float*)d_out;

  char* ws = (char*)d_ws;
  float* scoreb          = (float*)ws;                      // 64 B
  unsigned short* wscB   = (unsigned short*)(ws + 4096);    // 16 KB
  unsigned short* WvB    = (unsigned short*)(ws + 20480);   // 512 KB
  unsigned short* WoB    = (unsigned short*)(ws + 544768);  // 512 KB

  // Unconditional (deterministic, idempotent, host-side; enqueues nothing,
  // so graph capture is unaffected). Raises dynamic-LDS cap to 80 KB.
  hipFuncSetAttribute((const void*)tdcp_k1,
                      hipFuncAttributeMaxDynamicSharedMemorySize, 81920);

  tdcp_k0<<<136, 512, 0, stream>>>(q_param, in_w, in_b, out_w,
                                   scoreb, wscB, WvB, WoB);
  tdcp_k1<<<1024, 512, 81920, stream>>>(f0, f1, f2, f3, in_b,
                                        scoreb, wscB, WvB, WoB,
                                        out_b, gamma, beta, out);
}